// Round 15
// baseline (261.983 us; speedup 1.0000x reference)
//
#include <hip/hip_runtime.h>
#include <hip/hip_bf16.h>
#include <hip/hip_cooperative_groups.h>
#include <cstdint>

namespace cg = cooperative_groups;

// Problem constants (reference: N=16384, F=1024, H=256)
#define NR 16384
#define NF 1024
#define NH 256

typedef __bf16 bf16x8 __attribute__((ext_vector_type(8)));
typedef float f32x4 __attribute__((ext_vector_type(4)));
typedef unsigned short us8 __attribute__((ext_vector_type(8)));

static __device__ __forceinline__ unsigned short f2bf(float f) {
    unsigned u = __float_as_uint(f);
    u += 0x7FFFu + ((u >> 16) & 1u);   // RNE
    return (unsigned short)(u >> 16);
}

// ---------------------------------------------------------------------------
// MONO kernel (R14): cooperative launch, grid 256 x 512 thr, 1 block/CU.
//   phase P: pack weights (coalesced) + zero hdr      [was prep_kernel]
//   grid.sync()
//   phase F: fused GEMM pipeline — VERBATIM R12 internals (best fused,
//            52.2us measured): M=64 rows/block, frag-major LDS, MLP-16
//            weight pipeline (fb[8][2] / gb[8][2]), sync staging.
//   grid.sync()
//   phase Q: pairwise L1 (block -> jc = b&7 x ic = b>>3, sj[2048] tile)
//   grid.sync()
//   phase Z: block 0 writes out[0..3]
// RATIONALE: fused plateaued at 52us (4 MLP-16 configs); session gap
// (total - fused) = 108-134us every round with prep/pair ~5us each by
// arithmetic -> the 2 inter-kernel boundaries + launch overhead are the
// only part of the gap we own. R13's 2-blocks/CU bet refuted (occupancy
// 10.8% = blocks serialized; fused 96us).
// hdr: [0..63] mse cells, [64..127] pair cells, [129] nP, [130] nR
// ---------------------------------------------------------------------------
__global__ __launch_bounds__(512) void mono_kernel(
    const float* __restrict__ X,
    const float* __restrict__ We, const float* __restrict__ be,
    const float* __restrict__ Wd, const float* __restrict__ bd,
    const float* __restrict__ Wc, const int* __restrict__ s,
    const int* __restrict__ pv,
    unsigned short* __restrict__ Wepk, unsigned short* __restrict__ Wdpk,
    float* __restrict__ cP, float* __restrict__ cR,
    float* __restrict__ hdr, float* __restrict__ out) {
    __shared__ union {
        unsigned short xa[16384];        // 32 KB: X quarter, fragment-major
        struct {
            unsigned short gs[16384];    // 32 KB: g tile, fragment-major
            float credu[8][64];
            float msred[8];
        } p2;
        float sj[2048];                  // 8 KB: pair j-tile
    } u;
    cg::grid_group grid = cg::this_grid();
    const int t = threadIdx.x;
    const int b = blockIdx.x;

    // ================= phase P: pack weights + zero hdr ====================
    {
        if (b == 0 && t < 192) hdr[t] = 0.f;
        const int gid = b * 512 + t;
        if (gid < 32768) {               // We: k0 = gid>>8 (0..127), c = gid&255
            const int k0 = gid >> 8, c = gid & 255;
            const int kc = k0 >> 2, qq = k0 & 3, nb = c >> 4, li2 = c & 15;
            us8 v;
#pragma unroll
            for (int e = 0; e < 8; e++)
                v[e] = f2bf(We[(size_t)(k0 * 8 + e) * NH + c]);
            *(us8*)&Wepk[((size_t)(nb * 32 + kc)) * 512 + (qq * 16 + li2) * 8] = v;
        } else if (gid < 65536) {        // Wd: k0 = idx>>10 (0..31), c = idx&1023
            const int idx = gid - 32768;
            const int k0 = idx >> 10, c = idx & 1023;
            const int kc = k0 >> 2, qq = k0 & 3, nb = c >> 4, li2 = c & 15;
            us8 v;
#pragma unroll
            for (int e = 0; e < 8; e++)
                v[e] = f2bf(Wd[(size_t)(k0 * 8 + e) * NF + c]);
            *(us8*)&Wdpk[((size_t)(nb * 8 + kc)) * 512 + (qq * 16 + li2) * 8] = v;
        }
    }
    grid.sync();

    // ================= phase F: fused (R12 verbatim) =======================
    const int m0 = b * 64;
    const int w = t >> 6, lane = t & 63, q = lane >> 4, li = lane & 15;
    const int srow = w * 8;
    const int kcgl = lane >> 3;          // cell k-col 0..7
    const int sq2  = (lane >> 1) & 3;    // fragment q of this 16B
    const int sh   = lane & 1;           // element half

    // stage quarter 0
    {
        const float* xq = X + (size_t)m0 * NF + lane * 4;
#pragma unroll
        for (int rr = 0; rr < 8; ++rr) {
            const int r = srow + rr;
            float4 v4 = *(const float4*)(xq + (size_t)r * NF);
            ushort4 st = { f2bf(v4.x), f2bf(v4.y), f2bf(v4.z), f2bf(v4.w) };
            const int p = (sq2 * 16 + (r & 15)) ^ kcgl;
            *(ushort4*)&u.xa[(kcgl * 4 + (r >> 4)) * 512 + p * 8 + sh * 4] = st;
        }
    }
    __syncthreads();

    // phase 1: X @ We (8-deep B prefetch, MLP-16)
    const unsigned short* Bp[2];
#pragma unroll
    for (int j = 0; j < 2; j++)
        Bp[j] = Wepk + ((size_t)(w * 2 + j) * 32) * 512 + lane * 8;

    us8 fb[8][2];
#pragma unroll
    for (int z = 0; z < 8; ++z)
#pragma unroll
        for (int j = 0; j < 2; j++) fb[z][j] = *(const us8*)(Bp[j] + z * 512);

    f32x4 acc[4][2] = {};

#pragma unroll
    for (int ks = 0; ks < 4; ++ks) {
#pragma unroll
        for (int kcl = 0; kcl < 8; ++kcl) {
            const int kcg = ks * 8 + kcl;
            const int cb = kcg & 7;
#pragma unroll
            for (int mi = 0; mi < 4; ++mi) {
                bf16x8 a = __builtin_bit_cast(bf16x8,
                    *(const us8*)&u.xa[(kcl * 4 + mi) * 512 + (lane ^ kcl) * 8]);
                acc[mi][0] = __builtin_amdgcn_mfma_f32_16x16x32_bf16(
                    __builtin_bit_cast(bf16x8, fb[cb][0]), a, acc[mi][0], 0, 0, 0);
                acc[mi][1] = __builtin_amdgcn_mfma_f32_16x16x32_bf16(
                    __builtin_bit_cast(bf16x8, fb[cb][1]), a, acc[mi][1], 0, 0, 0);
            }
            if (kcg + 8 < 32) {
#pragma unroll
                for (int j = 0; j < 2; j++) fb[cb][j] = *(const us8*)(Bp[j] + (kcg + 8) * 512);
            }
        }
        __syncthreads();          // all waves done reading this quarter
        if (ks < 3) {             // synchronous staging of quarter ks+1
            const float* xq = X + (size_t)m0 * NF + (ks + 1) * 256 + lane * 4;
#pragma unroll
            for (int rr = 0; rr < 8; ++rr) {
                const int r = srow + rr;
                float4 v4 = *(const float4*)(xq + (size_t)r * NF);
                ushort4 st = { f2bf(v4.x), f2bf(v4.y), f2bf(v4.z), f2bf(v4.w) };
                const int p = (sq2 * 16 + (r & 15)) ^ kcgl;
                *(ushort4*)&u.xa[(kcgl * 4 + (r >> 4)) * 512 + p * 8 + sh * 4] = st;
            }
            __syncthreads();
        }
    }

    // epilogue: g -> fragment-major gs + critic partials
#pragma unroll
    for (int mi = 0; mi < 4; ++mi) {
        float csum = 0.f;
#pragma unroll
        for (int j = 0; j < 2; ++j) {
            const int colb = w * 32 + j * 16 + q * 4;
            float4 be4 = *(const float4*)&be[colb];
            float4 wc4 = *(const float4*)&Wc[colb];
            float v0 = acc[mi][j][0] + be4.x;
            float v1 = acc[mi][j][1] + be4.y;
            float v2 = acc[mi][j][2] + be4.z;
            float v3 = acc[mi][j][3] + be4.w;
            csum += v0 * wc4.x + v1 * wc4.y + v2 * wc4.z + v3 * wc4.w;
            ushort4 st = { f2bf(v0), f2bf(v1), f2bf(v2), f2bf(v3) };
            const int q2e = j * 2 + (q >> 1);
            const int p = (q2e * 16 + li) ^ w;
            *(ushort4*)&u.p2.gs[(w * 4 + mi) * 512 + p * 8 + (q & 1) * 4] = st;
        }
        csum += __shfl_down(csum, 32);
        csum += __shfl_down(csum, 16);
        if (lane < 16) u.p2.credu[w][mi * 16 + lane] = csum;
    }
    __syncthreads();   // gs + credu ready

    // in-block compaction of 64 critic values (wave 0)
    if (t < 64) {
        float cs = 0.f;
#pragma unroll
        for (int ww = 0; ww < 8; ++ww) cs += u.p2.credu[ww][t];
        bool pr = (s[m0 + t] == pv[0]);
        unsigned long long mk = __ballot(pr);
        int np = __popcll(mk);
        int baseP = 0, baseR = 0;
        if (t == 0) {
            baseP = atomicAdd((int*)hdr + 129, np);
            baseR = atomicAdd((int*)hdr + 130, 64 - np);
        }
        baseP = __shfl(baseP, 0);
        baseR = __shfl(baseR, 0);
        int offP = __popcll(mk & ((1ull << t) - 1ull));
        int offR = t - offP;
        if (pr) cP[baseP + offP] = cs; else cR[baseR + offR] = cs;
    }

    // phase 2: g @ Wd + MSE (4 passes x 256 cols; gb[8][2] upfront)
    float lsum = 0.f;
    const unsigned short* Wp = Wdpk + lane * 8;
#pragma unroll
    for (int pass = 0; pass < 4; ++pass) {
        const int nb0 = pass * 16 + w * 2;
        us8 gb[8][2];
#pragma unroll
        for (int z = 0; z < 8; ++z)
#pragma unroll
            for (int j = 0; j < 2; ++j)
                gb[z][j] = *(const us8*)(Wp + ((size_t)((nb0 + j) * 8 + z)) * 512);
        f32x4 a2[4][2] = {};
#pragma unroll
        for (int kc = 0; kc < 8; ++kc) {
#pragma unroll
            for (int mi = 0; mi < 4; ++mi) {
                bf16x8 af = __builtin_bit_cast(bf16x8,
                    *(const us8*)&u.p2.gs[(kc * 4 + mi) * 512 + (lane ^ kc) * 8]);
                a2[mi][0] = __builtin_amdgcn_mfma_f32_16x16x32_bf16(
                    __builtin_bit_cast(bf16x8, gb[kc][0]), af, a2[mi][0], 0, 0, 0);
                a2[mi][1] = __builtin_amdgcn_mfma_f32_16x16x32_bf16(
                    __builtin_bit_cast(bf16x8, gb[kc][1]), af, a2[mi][1], 0, 0, 0);
            }
        }
#pragma unroll
        for (int mi = 0; mi < 4; ++mi) {
            const size_t rowoff = (size_t)(m0 + mi * 16 + li) * NF;
#pragma unroll
            for (int j = 0; j < 2; ++j) {
                const int colb = pass * 256 + w * 32 + j * 16 + q * 4;
                float4 bd4 = *(const float4*)&bd[colb];
                float4 xr  = *(const float4*)&X[rowoff + colb];
                float d0 = a2[mi][j][0] + bd4.x - xr.x;
                float d1 = a2[mi][j][1] + bd4.y - xr.y;
                float d2 = a2[mi][j][2] + bd4.z - xr.z;
                float d3 = a2[mi][j][3] + bd4.w - xr.w;
                lsum += d0 * d0 + d1 * d1 + d2 * d2 + d3 * d3;
            }
        }
    }
#pragma unroll
    for (int o = 32; o; o >>= 1) lsum += __shfl_down(lsum, o);
    if (lane == 0) u.p2.msred[w] = lsum;
    __syncthreads();
    if (t == 0) {
        float ms = 0.f;
#pragma unroll
        for (int ww = 0; ww < 8; ++ww) ms += u.p2.msred[ww];
        atomicAdd(&hdr[b & 63], ms);
    }
    grid.sync();

    // ================= phase Q: pairwise L1 ================================
    {
        const int nP = ((const int*)hdr)[129];
        const int nRv = ((const int*)hdr)[130];
        const int jc = b & 7, ic = b >> 3;      // j-chunk of 2048, i-chunk of 512
        const int jb = jc * 2048;
        int jn = nRv - jb; if (jn < 0) jn = 0; if (jn > 2048) jn = 2048;
        if (jn > 0 && ic * 512 < nP) {
            for (int j = t; j < 2048; j += 512)
                u.sj[j] = (jb + j < nRv) ? cR[jb + j] : 0.f;
            __syncthreads();
            const int i = ic * 512 + t;
            const float ci = (i < nP) ? cP[i] : 0.f;
            float s0 = 0.f;
#pragma unroll 8
            for (int j4 = 0; j4 < 512; j4++) {
                float4 v = *(const float4*)&u.sj[j4 * 4];
                s0 += fabsf(ci - v.x) + fabsf(ci - v.y) +
                      fabsf(ci - v.z) + fabsf(ci - v.w);
            }
            s0 -= (float)(2048 - jn) * fabsf(ci);
            if (i >= nP) s0 = 0.f;
            float sum = s0;
#pragma unroll
            for (int o = 32; o; o >>= 1) sum += __shfl_down(sum, o);
            if ((t & 63) == 0 && sum != 0.f)
                atomicAdd(&hdr[64 + (b & 63)], sum);
        }
    }
    grid.sync();

    // ================= phase Z: finalize (block 0) =========================
    if (b == 0 && t == 0) {
        float ms = 0.f, ps = 0.f;
        for (int i = 0; i < 64; i++) { ms += hdr[i]; ps += hdr[64 + i]; }
        int np = ((const int*)hdr)[129];
        out[0] = ms / (float)((size_t)NR * NF);
        out[1] = (float)NR;
        out[2] = ps / (float)np;
        out[3] = (float)np;
    }
}

extern "C" void kernel_launch(void* const* d_in, const int* in_sizes, int n_in,
                              void* d_out, int out_size, void* d_ws, size_t ws_size,
                              hipStream_t stream) {
    const float* X  = (const float*)d_in[0];
    const float* We = (const float*)d_in[1];
    const float* be = (const float*)d_in[2];
    const float* Wd = (const float*)d_in[3];
    const float* bd = (const float*)d_in[4];
    const float* Wc = (const float*)d_in[5];
    // bc (d_in[6]) omitted: cancels in |c_i - c_j|
    const int*   s  = (const int*)d_in[7];
    const int*   pv = (const int*)d_in[8];

    char* ws = (char*)d_ws;
    float* hdr = (float*)ws;                                     // 192 f
    float* cP  = (float*)(ws + 1024);                            // 64 KB
    float* cR  = (float*)(ws + 1024 + 65536);                    // 64 KB
    unsigned short* Wepk = (unsigned short*)(ws + 1024 + 2 * 65536);  // 512 KB
    unsigned short* Wdpk = Wepk + (size_t)NH * NF;                    // 512 KB
    float* outp = (float*)d_out;

    void* args[] = {
        (void*)&X, (void*)&We, (void*)&be, (void*)&Wd, (void*)&bd,
        (void*)&Wc, (void*)&s, (void*)&pv, (void*)&Wepk, (void*)&Wdpk,
        (void*)&cP, (void*)&cR, (void*)&hdr, (void*)&outp
    };
    hipLaunchCooperativeKernel((void*)mono_kernel, dim3(256), dim3(512),
                               args, 0, stream);
}

// Round 16
// 182.909 us; speedup vs baseline: 1.4323x; 1.4323x over previous
//
#include <hip/hip_runtime.h>
#include <hip/hip_bf16.h>
#include <cstdint>

// Problem constants (reference: N=16384, F=1024, H=256)
#define NR 16384
#define NF 1024
#define NH 256

typedef __bf16 bf16x8 __attribute__((ext_vector_type(8)));
typedef float f32x4 __attribute__((ext_vector_type(4)));
typedef unsigned short us8 __attribute__((ext_vector_type(8)));

static __device__ __forceinline__ unsigned short f2bf(float f) {
    unsigned u = __float_as_uint(f);
    u += 0x7FFFu + ((u >> 16) & 1u);   // RNE
    return (unsigned short)(u >> 16);
}

// T4 barrier: every barrier in fused_kernel protects ONLY LDS data, so wait
// on lgkmcnt alone — do NOT drain vmcnt (that kills the 16-deep weight-load
// pipeline; __syncthreads() emits vmcnt(0) and was the quarter-boundary
// stall). sched_barrier(0) pins ordering (rule #18: compiler may hoist
// reg-only/LDS ops past inline-asm waits or raw s_barrier).
static __device__ __forceinline__ void lds_barrier() {
    asm volatile("s_waitcnt lgkmcnt(0)" ::: "memory");
    __builtin_amdgcn_sched_barrier(0);
    __builtin_amdgcn_s_barrier();
    __builtin_amdgcn_sched_barrier(0);
}

// Fragment-major packed weights (1 KB per cell = 64 lanes x 16 B):
//   Wepk[nb=16][kc=32][lane=q*16+n][e=8] = bf16(We[kc*32+q*8+e][nb*16+n])
//   Wdpk[nb=64][kc= 8][lane=q*16+n][e=8] = bf16(Wd[kc*32+q*8+e][nb*16+n])
// hdr: [0..63] mse cells, [64..127] pair cells, [128] pair ticket,
//      [129] nP (int), [130] nR (int)

// ---------------------------------------------------------------------------
// prep: coalesced packing (unchanged R12). 256 blocks x 256 thr.
// ---------------------------------------------------------------------------
__global__ __launch_bounds__(256) void prep_kernel(
    const float* __restrict__ We, const float* __restrict__ Wd,
    unsigned short* __restrict__ Wepk, unsigned short* __restrict__ Wdpk,
    float* __restrict__ hdr) {
    const int b = blockIdx.x, t = threadIdx.x;
    if (b == 0 && t < 192) hdr[t] = 0.f;
    if (b < 128) {
        const int k0 = b, c = t;                       // k rows 8*k0..8*k0+7
        const int kc = k0 >> 2, q = k0 & 3, nb = c >> 4, li = c & 15;
        us8 v;
#pragma unroll
        for (int e = 0; e < 8; e++)
            v[e] = f2bf(We[(size_t)(k0 * 8 + e) * NH + c]);
        *(us8*)&Wepk[((size_t)(nb * 32 + kc)) * 512 + (q * 16 + li) * 8] = v;
    } else {
        const int idx = b - 128;
        const int k0 = idx >> 2, c = (idx & 3) * 256 + t;
        const int kc = k0 >> 2, q = k0 & 3, nb = c >> 4, li = c & 15;
        us8 v;
#pragma unroll
        for (int e = 0; e < 8; e++)
            v[e] = f2bf(Wd[(size_t)(k0 * 8 + e) * NF + c]);
        *(us8*)&Wdpk[((size_t)(nb * 8 + kc)) * 512 + (q * 16 + li) * 8] = v;
    }
}

// ---------------------------------------------------------------------------
// FUSED (R15): R12 verbatim (best fused: 52.2us) EXCEPT all __syncthreads()
// -> lds_barrier() (lgkmcnt-only wait, T4).
// EVIDENCE: MLP-16 plateau at 52-53us across R5/R9/R13 regardless of
// prefetch depth — because __syncthreads()'s vmcnt(0) drains the weight
// pipeline at each of the 8 quarter barriers. No barrier here protects
// global data, so lgkmcnt(0) alone is sufficient; X-load -> ds_write deps
// still force their own per-load vmcnt waits (correctness unchanged).
// R14/R15 lessons recorded: cooperative mono-merge = 3x slowdown (reverted);
// total-minus-kernels ~ 100-110us is HARNESS-FIXED (1 launch showed the
// same gap) -> only kernel time matters.
// ---------------------------------------------------------------------------
__global__ __launch_bounds__(512) void fused_kernel(
    const float* __restrict__ X,
    const unsigned short* __restrict__ Wepk, const unsigned short* __restrict__ Wdpk,
    const float* __restrict__ be, const float* __restrict__ bd,
    const float* __restrict__ Wc, const int* __restrict__ s, const int* __restrict__ pv,
    float* __restrict__ cP, float* __restrict__ cR, float* __restrict__ hdr) {
    __shared__ union {
        unsigned short xa[16384];        // 32 KB: X quarter, fragment-major
        struct {
            unsigned short gs[16384];    // 32 KB: g tile, fragment-major
            float credu[8][64];
            float msred[8];
        } p2;
    } u;
    const int t = threadIdx.x;
    const int b = blockIdx.x, m0 = b * 64;
    const int w = t >> 6, lane = t & 63, q = lane >> 4, li = lane & 15;

    // staging geometry: wave w stages rows w*8..w*8+7; lane reads 16B at
    // col lane*4 (global contiguous 1KB per wave-row).
    // LDS cell (kcgl = lane>>3, mi = r>>4); slot s = sq2*16+(r&15), p = s^kcgl.
    const int srow = w * 8;
    const int kcgl = lane >> 3;          // cell k-col 0..7
    const int sq2  = (lane >> 1) & 3;    // fragment q of this 16B
    const int sh   = lane & 1;           // element half

    // ---------------- stage quarter 0 --------------------------------------
    {
        const float* xq = X + (size_t)m0 * NF + lane * 4;
#pragma unroll
        for (int rr = 0; rr < 8; ++rr) {
            const int r = srow + rr;
            float4 v4 = *(const float4*)(xq + (size_t)r * NF);
            ushort4 st = { f2bf(v4.x), f2bf(v4.y), f2bf(v4.z), f2bf(v4.w) };
            const int p = (sq2 * 16 + (r & 15)) ^ kcgl;
            *(ushort4*)&u.xa[(kcgl * 4 + (r >> 4)) * 512 + p * 8 + sh * 4] = st;
        }
    }
    lds_barrier();

    // ---------------- phase 1: X @ We (8-deep B prefetch, MLP-16) -----------
    const unsigned short* Bp[2];
#pragma unroll
    for (int j = 0; j < 2; j++)
        Bp[j] = Wepk + ((size_t)(w * 2 + j) * 32) * 512 + lane * 8;

    us8 fb[8][2];
#pragma unroll
    for (int z = 0; z < 8; ++z)
#pragma unroll
        for (int j = 0; j < 2; j++) fb[z][j] = *(const us8*)(Bp[j] + z * 512);

    f32x4 acc[4][2] = {};

#pragma unroll
    for (int ks = 0; ks < 4; ++ks) {
#pragma unroll
        for (int kcl = 0; kcl < 8; ++kcl) {
            const int kcg = ks * 8 + kcl;
            const int cb = kcg & 7;
#pragma unroll
            for (int mi = 0; mi < 4; ++mi) {
                bf16x8 a = __builtin_bit_cast(bf16x8,
                    *(const us8*)&u.xa[(kcl * 4 + mi) * 512 + (lane ^ kcl) * 8]);
                acc[mi][0] = __builtin_amdgcn_mfma_f32_16x16x32_bf16(
                    __builtin_bit_cast(bf16x8, fb[cb][0]), a, acc[mi][0], 0, 0, 0);
                acc[mi][1] = __builtin_amdgcn_mfma_f32_16x16x32_bf16(
                    __builtin_bit_cast(bf16x8, fb[cb][1]), a, acc[mi][1], 0, 0, 0);
            }
            if (kcg + 8 < 32) {
#pragma unroll
                for (int j = 0; j < 2; j++) fb[cb][j] = *(const us8*)(Bp[j] + (kcg + 8) * 512);
            }
        }
        lds_barrier();            // all waves done reading this quarter
        if (ks < 3) {             // synchronous staging of quarter ks+1
            const float* xq = X + (size_t)m0 * NF + (ks + 1) * 256 + lane * 4;
#pragma unroll
            for (int rr = 0; rr < 8; ++rr) {
                const int r = srow + rr;
                float4 v4 = *(const float4*)(xq + (size_t)r * NF);
                ushort4 st = { f2bf(v4.x), f2bf(v4.y), f2bf(v4.z), f2bf(v4.w) };
                const int p = (sq2 * 16 + (r & 15)) ^ kcgl;
                *(ushort4*)&u.xa[(kcgl * 4 + (r >> 4)) * 512 + p * 8 + sh * 4] = st;
            }
            lds_barrier();
        }
    }

    // epilogue: g -> fragment-major gs + critic partials (wave cols = cell w)
#pragma unroll
    for (int mi = 0; mi < 4; ++mi) {
        float csum = 0.f;
#pragma unroll
        for (int j = 0; j < 2; ++j) {
            const int colb = w * 32 + j * 16 + q * 4;
            float4 be4 = *(const float4*)&be[colb];
            float4 wc4 = *(const float4*)&Wc[colb];
            float v0 = acc[mi][j][0] + be4.x;
            float v1 = acc[mi][j][1] + be4.y;
            float v2 = acc[mi][j][2] + be4.z;
            float v3 = acc[mi][j][3] + be4.w;
            csum += v0 * wc4.x + v1 * wc4.y + v2 * wc4.z + v3 * wc4.w;
            ushort4 st = { f2bf(v0), f2bf(v1), f2bf(v2), f2bf(v3) };
            const int q2e = j * 2 + (q >> 1);
            const int p = (q2e * 16 + li) ^ w;
            *(ushort4*)&u.p2.gs[(w * 4 + mi) * 512 + p * 8 + (q & 1) * 4] = st;
        }
        csum += __shfl_down(csum, 32);
        csum += __shfl_down(csum, 16);
        if (lane < 16) u.p2.credu[w][mi * 16 + lane] = csum;
    }
    lds_barrier();     // gs + credu ready

    // in-block compaction of this block's 64 critic values (wave 0)
    if (t < 64) {
        float cs = 0.f;
#pragma unroll
        for (int ww = 0; ww < 8; ++ww) cs += u.p2.credu[ww][t];
        bool pr = (s[m0 + t] == pv[0]);
        unsigned long long mk = __ballot(pr);
        int np = __popcll(mk);
        int baseP = 0, baseR = 0;
        if (t == 0) {
            baseP = atomicAdd((int*)hdr + 129, np);
            baseR = atomicAdd((int*)hdr + 130, 64 - np);
        }
        baseP = __shfl(baseP, 0);
        baseR = __shfl(baseR, 0);
        int offP = __popcll(mk & ((1ull << t) - 1ull));
        int offR = t - offP;
        if (pr) cP[baseP + offP] = cs; else cR[baseR + offR] = cs;
    }

    // ---------------- phase 2: g @ Wd + MSE (4 passes x 256 cols) -----------
    // gb[8][2]: the pass's entire 16 weight loads issued upfront.
    float lsum = 0.f;
    const unsigned short* Wp = Wdpk + lane * 8;
#pragma unroll
    for (int pass = 0; pass < 4; ++pass) {
        const int nb0 = pass * 16 + w * 2;     // 2 n-blocks of 16 per wave
        us8 gb[8][2];
#pragma unroll
        for (int z = 0; z < 8; ++z)
#pragma unroll
            for (int j = 0; j < 2; ++j)
                gb[z][j] = *(const us8*)(Wp + ((size_t)((nb0 + j) * 8 + z)) * 512);
        f32x4 a2[4][2] = {};
#pragma unroll
        for (int kc = 0; kc < 8; ++kc) {
#pragma unroll
            for (int mi = 0; mi < 4; ++mi) {
                bf16x8 af = __builtin_bit_cast(bf16x8,
                    *(const us8*)&u.p2.gs[(kc * 4 + mi) * 512 + (lane ^ kc) * 8]);
                a2[mi][0] = __builtin_amdgcn_mfma_f32_16x16x32_bf16(
                    __builtin_bit_cast(bf16x8, gb[kc][0]), af, a2[mi][0], 0, 0, 0);
                a2[mi][1] = __builtin_amdgcn_mfma_f32_16x16x32_bf16(
                    __builtin_bit_cast(bf16x8, gb[kc][1]), af, a2[mi][1], 0, 0, 0);
            }
        }
        // MSE epilogue for this 256-col pass (X re-read inline, L3-warm)
#pragma unroll
        for (int mi = 0; mi < 4; ++mi) {
            const size_t rowoff = (size_t)(m0 + mi * 16 + li) * NF;
#pragma unroll
            for (int j = 0; j < 2; ++j) {
                const int colb = pass * 256 + w * 32 + j * 16 + q * 4;
                float4 bd4 = *(const float4*)&bd[colb];
                float4 xr  = *(const float4*)&X[rowoff + colb];
                float d0 = a2[mi][j][0] + bd4.x - xr.x;
                float d1 = a2[mi][j][1] + bd4.y - xr.y;
                float d2 = a2[mi][j][2] + bd4.z - xr.z;
                float d3 = a2[mi][j][3] + bd4.w - xr.w;
                lsum += d0 * d0 + d1 * d1 + d2 * d2 + d3 * d3;
            }
        }
    }
#pragma unroll
    for (int o = 32; o; o >>= 1) lsum += __shfl_down(lsum, o);
    if (lane == 0) u.p2.msred[w] = lsum;
    lds_barrier();
    if (t == 0) {
        float ms = 0.f;
#pragma unroll
        for (int ww = 0; ww < 8; ++ww) ms += u.p2.msred[ww];
        atomicAdd(&hdr[b & 63], ms);
    }
}

// ---------------------------------------------------------------------------
// compacted pairwise L1 + fused finalize (last-ticket block writes d_out)
// grid (16 j-chunks x 32 i-chunks of 512)
// ---------------------------------------------------------------------------
__global__ __launch_bounds__(256) void pair_fin_kernel(
    const float* __restrict__ cP, const float* __restrict__ cR,
    float* __restrict__ hdr, float* __restrict__ out) {
    __shared__ float sj[1024];
    __shared__ float red[256];
    __shared__ int win;
    const int nP = ((const int*)hdr)[129];
    const int nR = ((const int*)hdr)[130];
    const int jb = blockIdx.x * 1024;
    int jn = nR - jb; if (jn < 0) jn = 0; if (jn > 1024) jn = 1024;
    float sum = 0.f;
    if (jn > 0 && blockIdx.y * 512 < nP) {
        for (int j = threadIdx.x; j < 1024; j += 256)
            sj[j] = (jb + j < nR) ? cR[jb + j] : 0.f;
        __syncthreads();
        const int a0 = blockIdx.y * 512 + threadIdx.x, a1 = a0 + 256;
        const float ca0 = (a0 < nP) ? cP[a0] : 0.f;
        const float ca1 = (a1 < nP) ? cP[a1] : 0.f;
        float s0 = 0.f, s1 = 0.f;
#pragma unroll 8
        for (int j4 = 0; j4 < 256; j4++) {
            float4 v = *(const float4*)&sj[j4 * 4];
            s0 += fabsf(ca0 - v.x) + fabsf(ca0 - v.y) + fabsf(ca0 - v.z) + fabsf(ca0 - v.w);
            s1 += fabsf(ca1 - v.x) + fabsf(ca1 - v.y) + fabsf(ca1 - v.z) + fabsf(ca1 - v.w);
        }
        float pad = (float)(1024 - jn);
        s0 -= pad * fabsf(ca0);
        s1 -= pad * fabsf(ca1);
        if (a0 >= nP) s0 = 0.f;
        if (a1 >= nP) s1 = 0.f;
        sum = s0 + s1;
#pragma unroll
        for (int o = 32; o; o >>= 1) sum += __shfl_down(sum, o);
        if ((threadIdx.x & 63) == 0 && sum != 0.f)
            atomicAdd(&hdr[64 + ((blockIdx.y * 16 + blockIdx.x) & 63)], sum);
    }
    __threadfence();
    __syncthreads();
    if (threadIdx.x == 0)
        win = (atomicAdd((int*)(hdr + 128), 1) == 16 * 32 - 1) ? 1 : 0;
    __syncthreads();
    if (win) {
        float v = (threadIdx.x < 128) ? atomicAdd(&hdr[threadIdx.x], 0.f) : 0.f;
        red[threadIdx.x] = v;
        __syncthreads();
        if (threadIdx.x == 0) {
            float ms = 0.f, ps = 0.f;
            for (int i = 0; i < 64; i++) { ms += red[i]; ps += red[64 + i]; }
            int np = atomicAdd((int*)(hdr + 129), 0);
            out[0] = ms / (float)((size_t)NR * NF);
            out[1] = (float)NR;
            out[2] = ps / (float)np;
            out[3] = (float)np;
        }
    }
}

extern "C" void kernel_launch(void* const* d_in, const int* in_sizes, int n_in,
                              void* d_out, int out_size, void* d_ws, size_t ws_size,
                              hipStream_t stream) {
    const float* X  = (const float*)d_in[0];
    const float* We = (const float*)d_in[1];
    const float* be = (const float*)d_in[2];
    const float* Wd = (const float*)d_in[3];
    const float* bd = (const float*)d_in[4];
    const float* Wc = (const float*)d_in[5];
    // bc (d_in[6]) omitted: cancels in |c_i - c_j|
    const int*   s  = (const int*)d_in[7];
    const int*   pv = (const int*)d_in[8];

    char* ws = (char*)d_ws;
    float* hdr = (float*)ws;                                     // 192 f
    float* cP  = (float*)(ws + 1024);                            // 64 KB
    float* cR  = (float*)(ws + 1024 + 65536);                    // 64 KB
    unsigned short* Wepk = (unsigned short*)(ws + 1024 + 2 * 65536);  // 512 KB
    unsigned short* Wdpk = Wepk + (size_t)NH * NF;                    // 512 KB

    prep_kernel<<<256, 256, 0, stream>>>(We, Wd, Wepk, Wdpk, hdr);
    fused_kernel<<<256, 512, 0, stream>>>(X, Wepk, Wdpk, be, bd, Wc, s, pv, cP, cR, hdr);
    pair_fin_kernel<<<dim3(16, 32), 256, 0, stream>>>(cP, cR, hdr, (float*)d_out);
}